// Round 6
// baseline (337.064 us; speedup 1.0000x reference)
//
#include <hip/hip_runtime.h>

// Problem constants (fp32 RQ-VAE nearest-codebook step)
#define Bn 8192
#define Kn 8192
#define Dn 512

typedef _Float16 half8 __attribute__((ext_vector_type(8)));
typedef float floatx4 __attribute__((ext_vector_type(4)));
typedef unsigned long long u64;

// Order-preserving map float -> u32 (monotone under unsigned compare, finite inputs)
__device__ __forceinline__ unsigned int fkey(float f) {
    unsigned int u = __float_as_uint(f);
    return (u & 0x80000000u) ? ~u : (u | 0x80000000u);
}

// ---------------- kernel: e_sq[k] = ||E[k]||^2 ----------------
__global__ __launch_bounds__(256) void esq_kernel(const float* __restrict__ E,
                                                  float* __restrict__ esq) {
    int wave = threadIdx.x >> 6;
    int lane = threadIdx.x & 63;
    int k = blockIdx.x * 4 + wave;
    const float4* row = (const float4*)(E + (size_t)k * Dn);
    float4 v0 = row[lane];
    float4 v1 = row[64 + lane];
    float s = v0.x*v0.x + v0.y*v0.y + v0.z*v0.z + v0.w*v0.w
            + v1.x*v1.x + v1.y*v1.y + v1.z*v1.z + v1.w*v1.w;
    #pragma unroll
    for (int off = 32; off > 0; off >>= 1) s += __shfl_down(s, off, 64);
    if (lane == 0) esq[k] = s;
}

// ---------------- kernel: fp32 -> (hi,lo) f16 split, PACKED fragment layout ---
// G[panel][chunk][slot]*8 halves, panel = 128 rows, chunk = 32 k-halves,
//   slot(row128, kq) = (row128>>6)*256 + ((row128>>4)&3)*64 + kq*16 + (row128&15)
// A fragment read for (wy,mi,chunk) is then base + lane*16B: coalesced dwordx4.
// Reads here are coalesced 128B/row segments; scattered 16B writes (L2 absorbs).
__global__ __launch_bounds__(256) void convert_packed(
    const float* __restrict__ src,
    _Float16* __restrict__ Gh, _Float16* __restrict__ Gl)
{
    const int panel = blockIdx.x >> 4;      // 64 panels of 128 rows
    const int chunk = blockIdx.x & 15;      // 16 chunks of 32 halves
    const int t = threadIdx.x;
    const int row = t >> 1;                 // [0,128)
    const int kh  = (t & 1) * 16;           // half-offset within chunk
    const float* p = &src[(size_t)(panel * 128 + row) * Dn + chunk * 32 + kh];
    float4 v[4];
    v[0] = *(const float4*)(p + 0);
    v[1] = *(const float4*)(p + 4);
    v[2] = *(const float4*)(p + 8);
    v[3] = *(const float4*)(p + 12);
    const int slotbase = ((row >> 6) << 8) + (((row >> 4) & 3) << 6) + (row & 15);
    #pragma unroll
    for (int j = 0; j < 2; ++j) {
        half8 h, l;
        #pragma unroll
        for (int q = 0; q < 2; ++q) {
            const float4 w = v[j * 2 + q];
            h[q*4+0]=(_Float16)w.x; l[q*4+0]=(_Float16)(w.x-(float)h[q*4+0]);
            h[q*4+1]=(_Float16)w.y; l[q*4+1]=(_Float16)(w.y-(float)h[q*4+1]);
            h[q*4+2]=(_Float16)w.z; l[q*4+2]=(_Float16)(w.z-(float)h[q*4+2]);
            h[q*4+3]=(_Float16)w.w; l[q*4+3]=(_Float16)(w.w-(float)h[q*4+3]);
        }
        const int kq = (t & 1) * 2 + j;
        const size_t off = ((size_t)(panel * 16 + chunk) * 512
                            + slotbase + kq * 16) * 8;
        *(half8*)&Gh[off] = h;
        *(half8*)&Gl[off] = l;
    }
}

// ---------------- kernel: MFMA cross-term + fused argmin, NO tile LDS --------
// dist(b,k) = e_sq[k] - 2*(xh.eh + xh.el + xl.eh);  128x128 block tile,
// 4 waves of 64x64 (4x4 of 16x16x32 f16 MFMA). Fragments load DIRECTLY from
// the packed global layout (base + lane*16B, coalesced 1KB/instr) -> no LDS
// staging, no __syncthreads in the K-loop, no barrier vmcnt drain.
__global__ __launch_bounds__(256, 4) void argmin_direct(
    const _Float16* __restrict__ Xh, const _Float16* __restrict__ Xl,
    const _Float16* __restrict__ Eh, const _Float16* __restrict__ El,
    const float* __restrict__ esq, u64* __restrict__ best)
{
    __shared__ u64 red[128][2];

    const int tid  = threadIdx.x;
    const int mb   = blockIdx.x >> 6;      // 64 m-blocks
    const int nb   = blockIdx.x & 63;      // 64 n-blocks
    const int m0   = mb * 128, n0 = nb * 128;
    const int lane = tid & 63, wave = tid >> 6;
    const int wx   = wave & 1, wy = wave >> 1;   // wave tile origin (wy*64, wx*64)
    const int colg = lane & 15, quad = lane >> 4;

    floatx4 acc[4][4];
    #pragma unroll
    for (int i = 0; i < 4; ++i)
        #pragma unroll
        for (int j = 0; j < 4; ++j) acc[i][j] = {0.f, 0.f, 0.f, 0.f};

    // fragment bases: panel stride 65536 halves, chunk stride 4096,
    // slot = (wy|wx)*256 + mi*64 + lane  (x8 halves)
    const _Float16* aH = Xh + (size_t)mb * 65536 + (size_t)(wy * 256 + lane) * 8;
    const _Float16* aL = Xl + (size_t)mb * 65536 + (size_t)(wy * 256 + lane) * 8;
    const _Float16* bHp = Eh + (size_t)nb * 65536 + (size_t)(wx * 256 + lane) * 8;
    const _Float16* bLp = El + (size_t)nb * 65536 + (size_t)(wx * 256 + lane) * 8;

    #pragma unroll 2
    for (int c = 0; c < 16; ++c) {
        const size_t gb = (size_t)c * 4096;
        half8 bh[4], bl[4];
        #pragma unroll
        for (int ni = 0; ni < 4; ++ni) {
            bh[ni] = *(const half8*)(bHp + gb + ni * 512);
            bl[ni] = *(const half8*)(bLp + gb + ni * 512);
        }
        #pragma unroll
        for (int mi = 0; mi < 4; ++mi) {
            half8 ah = *(const half8*)(aH + gb + mi * 512);
            half8 al = *(const half8*)(aL + gb + mi * 512);
            #pragma unroll
            for (int ni = 0; ni < 4; ++ni) {
                acc[mi][ni] = __builtin_amdgcn_mfma_f32_16x16x32_f16(ah, bh[ni], acc[mi][ni], 0, 0, 0);
                acc[mi][ni] = __builtin_amdgcn_mfma_f32_16x16x32_f16(ah, bl[ni], acc[mi][ni], 0, 0, 0);
                acc[mi][ni] = __builtin_amdgcn_mfma_f32_16x16x32_f16(al, bh[ni], acc[mi][ni], 0, 0, 0);
            }
        }
    }

    // epilogue: dist = esq - 2*cross, per-row argmin over this block's 128 cols.
    // C/D layout: col = lane&15, row = quad*4 + reg  (m89-verified)
    #pragma unroll
    for (int mi = 0; mi < 4; ++mi) {
        #pragma unroll
        for (int r = 0; r < 4; ++r) {
            float bv = INFINITY; int bi = 0;
            #pragma unroll
            for (int ni = 0; ni < 4; ++ni) {   // ascending col -> '<' keeps low idx
                int c = wx * 64 + ni * 16 + colg;
                float dv = esq[n0 + c] - 2.0f * acc[mi][ni][r];
                if (dv < bv) { bv = dv; bi = n0 + c; }
            }
            u64 key = ((u64)fkey(bv) << 32) | (u64)(unsigned int)bi;
            #pragma unroll
            for (int off = 1; off < 16; off <<= 1) {
                u64 o = __shfl_xor(key, off);
                if (o < key) key = o;
            }
            if (colg == 0) red[wy * 64 + mi * 16 + quad * 4 + r][wx] = key;
        }
    }
    __syncthreads();
    if (tid < 128) {
        u64 a = red[tid][0], b = red[tid][1];
        best[(size_t)(m0 + tid) * 64 + nb] = (b < a) ? b : a;
    }
}

// ---------------- fallback (round-1 fp32 path, used only if ws too small) ----
#define KSPLIT 16
#define LDSW 132
__global__ __launch_bounds__(256, 2) void argmin_fp32(
    const float* __restrict__ X, const float* __restrict__ E,
    const float* __restrict__ esq, u64* __restrict__ best)
{
    __shared__ __align__(16) float Xs[16][LDSW];
    __shared__ __align__(16) float Es[16][LDSW];
    __shared__ u64 red[128][16];
    const int tid = threadIdx.x;
    const int tx = tid & 15, ty = tid >> 4;
    const int rowTile = blockIdx.x / KSPLIT;
    const int split   = blockIdx.x % KSPLIT;
    const int m0 = rowTile * 128;
    const int kbase = split * (Kn / KSPLIT);
    float bestv[8]; int besti[8];
    #pragma unroll
    for (int i = 0; i < 8; ++i) { bestv[i] = INFINITY; besti[i] = 0; }
    const int ldRow = tid >> 2, ldD = (tid & 3) * 4;
    for (int kt = 0; kt < (Kn / KSPLIT) / 128; ++kt) {
        const int k0 = kbase + kt * 128;
        float acc[8][8] = {};
        for (int dc = 0; dc < Dn / 16; ++dc) {
            const int d0 = dc * 16;
            float4 xa = *(const float4*)&X[(size_t)(m0 + ldRow)      * Dn + d0 + ldD];
            float4 xb = *(const float4*)&X[(size_t)(m0 + 64 + ldRow) * Dn + d0 + ldD];
            float4 ea = *(const float4*)&E[(size_t)(k0 + ldRow)      * Dn + d0 + ldD];
            float4 eb = *(const float4*)&E[(size_t)(k0 + 64 + ldRow) * Dn + d0 + ldD];
            __syncthreads();
            Xs[ldD+0][ldRow] = xa.x; Xs[ldD+1][ldRow] = xa.y;
            Xs[ldD+2][ldRow] = xa.z; Xs[ldD+3][ldRow] = xa.w;
            Xs[ldD+0][64+ldRow] = xb.x; Xs[ldD+1][64+ldRow] = xb.y;
            Xs[ldD+2][64+ldRow] = xb.z; Xs[ldD+3][64+ldRow] = xb.w;
            Es[ldD+0][ldRow] = ea.x; Es[ldD+1][ldRow] = ea.y;
            Es[ldD+2][ldRow] = ea.z; Es[ldD+3][ldRow] = ea.w;
            Es[ldD+0][64+ldRow] = eb.x; Es[ldD+1][64+ldRow] = eb.y;
            Es[ldD+2][64+ldRow] = eb.z; Es[ldD+3][64+ldRow] = eb.w;
            __syncthreads();
            #pragma unroll
            for (int d = 0; d < 16; ++d) {
                float a8[8], b8[8];
                *(float4*)&a8[0] = *(const float4*)&Xs[d][4*ty];
                *(float4*)&a8[4] = *(const float4*)&Xs[d][64 + 4*ty];
                *(float4*)&b8[0] = *(const float4*)&Es[d][4*tx];
                *(float4*)&b8[4] = *(const float4*)&Es[d][64 + 4*tx];
                #pragma unroll
                for (int i = 0; i < 8; ++i)
                    #pragma unroll
                    for (int j = 0; j < 8; ++j) acc[i][j] += a8[i] * b8[j];
            }
        }
        #pragma unroll
        for (int j = 0; j < 8; ++j) {
            const int c = k0 + ((j < 4) ? (4*tx + j) : (64 + 4*tx + (j - 4)));
            const float eq = esq[c];
            #pragma unroll
            for (int i = 0; i < 8; ++i) {
                float dval = eq - 2.0f * acc[i][j];
                if (dval < bestv[i]) { bestv[i] = dval; besti[i] = c; }
            }
        }
    }
    #pragma unroll
    for (int i = 0; i < 8; ++i) {
        int rloc = (i < 4) ? (4*ty + i) : (64 + 4*ty + (i - 4));
        red[rloc][tx] = ((u64)fkey(bestv[i]) << 32) | (u64)(unsigned int)besti[i];
    }
    __syncthreads();
    if (tid < 128) {
        u64 m = red[tid][0];
        #pragma unroll
        for (int t = 1; t < 16; ++t) { u64 v = red[tid][t]; if (v < m) m = v; }
        best[(size_t)(m0 + tid) * KSPLIT + split] = m;
    }
}

// ---------------- kernel: reduce splits, write index + residual ----------------
// 2 rows per block: threads [0,128) -> row 2b, [128,256) -> row 2b+1.
__global__ __launch_bounds__(256) void finalize_kernel(
    const float* __restrict__ X, const float* __restrict__ E,
    const u64* __restrict__ best, float* __restrict__ out, int nsplits)
{
    __shared__ int sidx[2];
    const int half = threadIdx.x >> 7;
    const int t    = threadIdx.x & 127;
    const int b    = blockIdx.x * 2 + half;
    if (t < 64) {
        u64 v = (t < nsplits) ? best[(size_t)b * nsplits + t] : ~0ull;
        #pragma unroll
        for (int off = 1; off < 64; off <<= 1) {
            u64 o = __shfl_xor(v, off);
            if (o < v) v = o;
        }
        if (t == 0) {
            int idx = (int)(unsigned int)(v & 0xFFFFFFFFull);
            sidx[half] = idx;
            out[b] = (float)idx;
        }
    }
    __syncthreads();
    const int idx = sidx[half];
    float4 x = ((const float4*)(X + (size_t)b * Dn))[t];
    float4 e = ((const float4*)(E + (size_t)idx * Dn))[t];
    float4 r; r.x = x.x - e.x; r.y = x.y - e.y; r.z = x.z - e.z; r.w = x.w - e.w;
    ((float4*)(out + Bn + (size_t)b * Dn))[t] = r;
}

extern "C" void kernel_launch(void* const* d_in, const int* in_sizes, int n_in,
                              void* d_out, int out_size, void* d_ws, size_t ws_size,
                              hipStream_t stream) {
    const float* X = (const float*)d_in[0];   // previous_residual [B, D]
    const float* E = (const float*)d_in[1];   // codebook_embeddings [K, D]
    float* out = (float*)d_out;               // [B] idx-as-float ++ [B*D] residual

    // fast-path ws layout: esq (32KB) | Xh | Xl | Eh | El (8MB each) | best (4MB)
    const size_t HB = (size_t)Bn * Dn * sizeof(_Float16);   // 8 MB
    const size_t NEED = 32768 + 4 * HB + (size_t)Bn * 64 * sizeof(u64);

    float* esq = (float*)d_ws;

    if (ws_size >= NEED) {
        _Float16* Xh = (_Float16*)((char*)d_ws + 32768);
        _Float16* Xl = (_Float16*)((char*)d_ws + 32768 + HB);
        _Float16* Eh = (_Float16*)((char*)d_ws + 32768 + 2 * HB);
        _Float16* El = (_Float16*)((char*)d_ws + 32768 + 3 * HB);
        u64* best    = (u64*)((char*)d_ws + 32768 + 4 * HB);
        esq_kernel<<<Kn / 4, 256, 0, stream>>>(E, esq);
        convert_packed<<<1024, 256, 0, stream>>>(X, Xh, Xl);
        convert_packed<<<1024, 256, 0, stream>>>(E, Eh, El);
        argmin_direct<<<64 * 64, 256, 0, stream>>>(Xh, Xl, Eh, El, esq, best);
        finalize_kernel<<<Bn / 2, 256, 0, stream>>>(X, E, best, out, 64);
    } else {
        u64* best = (u64*)((char*)d_ws + 32768);
        esq_kernel<<<Kn / 4, 256, 0, stream>>>(E, esq);
        argmin_fp32<<<(Bn / 128) * KSPLIT, 256, 0, stream>>>(X, E, esq, best);
        finalize_kernel<<<Bn / 2, 256, 0, stream>>>(X, E, best, out, KSPLIT);
    }
}

// Round 7
// 224.422 us; speedup vs baseline: 1.5019x; 1.5019x over previous
//
#include <hip/hip_runtime.h>

// Problem constants (fp32 RQ-VAE nearest-codebook step)
#define Bn 8192
#define Kn 8192
#define Dn 512
#define WINDOW 0.25f   // refine window: ~9.6 sigma of hi-only distance error diff

typedef _Float16 half8 __attribute__((ext_vector_type(8)));
typedef float floatx4 __attribute__((ext_vector_type(4)));
typedef unsigned long long u64;

// Order-preserving map float -> u32 (monotone under unsigned compare, finite inputs)
__device__ __forceinline__ unsigned int fkey(float f) {
    unsigned int u = __float_as_uint(f);
    return (u & 0x80000000u) ? ~u : (u | 0x80000000u);
}
__device__ __forceinline__ float unfkey(unsigned int v) {
    unsigned int u = (v & 0x80000000u) ? (v & 0x7fffffffu) : ~v;
    return __uint_as_float(u);
}

// async global->LDS, 16B per lane (global_load_lds_dwordx4)
__device__ __forceinline__ void gld16(const _Float16* g, _Float16* l) {
    __builtin_amdgcn_global_load_lds(
        (const __attribute__((address_space(1))) unsigned int*)g,
        (__attribute__((address_space(3))) unsigned int*)l, 16, 0, 0);
}

// ---------------- kernel: e_sq[k] = ||E[k]||^2 (fp32 exact) ----------------
__global__ __launch_bounds__(256) void esq_kernel(const float* __restrict__ E,
                                                  float* __restrict__ esq) {
    int wave = threadIdx.x >> 6;
    int lane = threadIdx.x & 63;
    int k = blockIdx.x * 4 + wave;
    const float4* row = (const float4*)(E + (size_t)k * Dn);
    float4 v0 = row[lane];
    float4 v1 = row[64 + lane];
    float s = v0.x*v0.x + v0.y*v0.y + v0.z*v0.z + v0.w*v0.w
            + v1.x*v1.x + v1.y*v1.y + v1.z*v1.z + v1.w*v1.w;
    #pragma unroll
    for (int off = 32; off > 0; off >>= 1) s += __shfl_down(s, off, 64);
    if (lane == 0) esq[k] = s;
}

// ---------------- kernel: fp32 -> f16 (hi only), PACKED fragment layout ------
// G[panel][chunk][slot]*8 halves, panel = 128 rows, chunk = 32 k-halves,
//   slot(row128, kq) = (row128>>6)*256 + ((row128>>4)&3)*64 + kq*16 + (row128&15)
// blocks [0,1024) pack X, [1024,2048) pack E.
__global__ __launch_bounds__(256) void convert_hi(
    const float* __restrict__ X, const float* __restrict__ E,
    _Float16* __restrict__ Xh, _Float16* __restrict__ Eh)
{
    const bool isE = blockIdx.x >= 1024;
    const int pc = blockIdx.x & 1023;
    const int panel = pc >> 4;              // 64 panels of 128 rows
    const int chunk = pc & 15;              // 16 chunks of 32 halves
    const float* src = isE ? E : X;
    _Float16* dst = isE ? Eh : Xh;
    const int t = threadIdx.x;
    const int row = t >> 1;                 // [0,128)
    const int kh  = (t & 1) * 16;
    const float* p = &src[(size_t)(panel * 128 + row) * Dn + chunk * 32 + kh];
    float4 v[4];
    v[0] = *(const float4*)(p + 0);
    v[1] = *(const float4*)(p + 4);
    v[2] = *(const float4*)(p + 8);
    v[3] = *(const float4*)(p + 12);
    const int slotbase = ((row >> 6) << 8) + (((row >> 4) & 3) << 6) + (row & 15);
    #pragma unroll
    for (int j = 0; j < 2; ++j) {
        half8 h;
        #pragma unroll
        for (int q = 0; q < 2; ++q) {
            const float4 w = v[j * 2 + q];
            h[q*4+0]=(_Float16)w.x; h[q*4+1]=(_Float16)w.y;
            h[q*4+2]=(_Float16)w.z; h[q*4+3]=(_Float16)w.w;
        }
        const int kq = (t & 1) * 2 + j;
        const size_t off = ((size_t)(panel * 16 + chunk) * 512
                            + slotbase + kq * 16) * 8;
        *(half8*)&dst[off] = h;
    }
}

// ---------------- kernel: hi-only MFMA + top-2-per-64-col-group argmin -------
// d~(b,k) = e_sq[k] - 2*(xh.eh);  128x128 block tile, 4 waves of 64x64
// (4x4 of 16x16x32 f16 MFMA), BK=64 staged per barrier pair. Packed inputs:
// staging slot t -> lds slot t (contiguous both sides), fragment reads
// base + lane*16B (zero bank conflicts). Stores top-2 approx candidates per
// (row, 64-col group) for the exact-refine pass.
__global__ __launch_bounds__(256, 4) void argmin_hi(
    const _Float16* __restrict__ Xh, const _Float16* __restrict__ Eh,
    const float* __restrict__ esq, u64* __restrict__ best)
{
    __shared__ __align__(16) _Float16 sX[8192];   // 2 chunks of X panel rows
    __shared__ __align__(16) _Float16 sE[8192];

    const int tid  = threadIdx.x;
    const int mb   = blockIdx.x >> 6;      // 64 m-blocks
    const int nb   = blockIdx.x & 63;      // 64 n-blocks
    const int m0   = mb * 128, n0 = nb * 128;
    const int lane = tid & 63, wave = tid >> 6;
    const int wx   = wave & 1, wy = wave >> 1;
    const int colg = lane & 15, quad = lane >> 4;

    floatx4 acc[4][4];
    #pragma unroll
    for (int i = 0; i < 4; ++i)
        #pragma unroll
        for (int j = 0; j < 4; ++j) acc[i][j] = {0.f, 0.f, 0.f, 0.f};

    const _Float16* gX = Xh + (size_t)mb * 65536 + tid * 8;
    const _Float16* gE = Eh + (size_t)nb * 65536 + tid * 8;
    _Float16* dX = &sX[tid * 8];
    _Float16* dE = &sE[tid * 8];

    const int aoff = wy * 2048 + lane * 8;   // + s*4096 + mi*512
    const int boff = wx * 2048 + lane * 8;   // + s*4096 + ni*512

    for (int c = 0; c < 8; ++c) {            // 8 x BK=64 halves
        const size_t gb = (size_t)c * 8192;
        __syncthreads();                     // prev iteration's LDS reads done
        gld16(gX + gb,        dX);
        gld16(gX + gb + 2048, dX + 2048);
        gld16(gX + gb + 4096, dX + 4096);
        gld16(gX + gb + 6144, dX + 6144);
        gld16(gE + gb,        dE);
        gld16(gE + gb + 2048, dE + 2048);
        gld16(gE + gb + 4096, dE + 4096);
        gld16(gE + gb + 6144, dE + 6144);
        __syncthreads();                     // drains vmcnt -> data visible

        #pragma unroll
        for (int s = 0; s < 2; ++s) {        // 2 k-steps of 32 halves
            const int so = s * 4096;
            half8 bh[4];
            #pragma unroll
            for (int ni = 0; ni < 4; ++ni)
                bh[ni] = *(const half8*)&sE[boff + so + ni * 512];
            #pragma unroll
            for (int mi = 0; mi < 4; ++mi) {
                half8 ah = *(const half8*)&sX[aoff + so + mi * 512];
                #pragma unroll
                for (int ni = 0; ni < 4; ++ni)
                    acc[mi][ni] = __builtin_amdgcn_mfma_f32_16x16x32_f16(
                        ah, bh[ni], acc[mi][ni], 0, 0, 0);
            }
        }
    }

    // epilogue: per (row, this wave's 64 cols) keep top-2 approx candidates.
    // C/D layout: col = lane&15, row = quad*4 + reg (m89-verified).
    float eq[4];
    #pragma unroll
    for (int ni = 0; ni < 4; ++ni) eq[ni] = esq[n0 + wx * 64 + ni * 16 + colg];

    #pragma unroll
    for (int mi = 0; mi < 4; ++mi) {
        #pragma unroll
        for (int r = 0; r < 4; ++r) {
            u64 m1 = ~0ull, m2 = ~0ull;
            #pragma unroll
            for (int ni = 0; ni < 4; ++ni) {
                const int c = n0 + wx * 64 + ni * 16 + colg;
                const float dv = eq[ni] - 2.0f * acc[mi][ni][r];
                const u64 k = ((u64)fkey(dv) << 32) | (u64)(unsigned int)c;
                if (k < m1) { m2 = m1; m1 = k; } else if (k < m2) m2 = k;
            }
            #pragma unroll
            for (int off = 1; off < 16; off <<= 1) {   // merge across 16 lanes
                const u64 p1 = __shfl_xor(m1, off);
                const u64 p2 = __shfl_xor(m2, off);
                if (p1 < m1) { m2 = (m1 < p2) ? m1 : p2; m1 = p1; }
                else         { m2 = (p1 < m2) ? p1 : m2; }
            }
            if (colg == 0) {
                const int row = m0 + wy * 64 + mi * 16 + quad * 4 + r;
                u64* dst = &best[((size_t)row * 128 + nb * 2 + wx) * 2];
                dst[0] = m1; dst[1] = m2;
            }
        }
    }
}

// ---------------- kernel: exact refine of shortlist + residual (fused) -------
// Per row: 256 stored candidates -> prune to approx-min + WINDOW -> exact fp32
// distance for survivors -> argmin (ties: lowest index) -> index + residual.
__global__ __launch_bounds__(256) void refine_kernel(
    const float* __restrict__ X, const float* __restrict__ E,
    const float* __restrict__ esq, const u64* __restrict__ best,
    float* __restrict__ out)
{
    __shared__ float xrow[512];
    __shared__ u64 amin;            // approx min key
    __shared__ u64 skey;            // exact best key
    __shared__ unsigned scnt;
    __shared__ unsigned cand[256];

    const int b = blockIdx.x, t = threadIdx.x;
    const int lane = t & 63, wave = t >> 6;

    if (t == 0) { amin = ~0ull; skey = ~0ull; scnt = 0u; }
    if (t < 128) ((float4*)xrow)[t] = ((const float4*)(X + (size_t)b * Dn))[t];
    __syncthreads();

    const u64 key = best[(size_t)b * 256 + t];
    atomicMin(&amin, key);
    __syncthreads();

    const float thresh = unfkey((unsigned int)(amin >> 32)) + WINDOW;
    if (unfkey((unsigned int)(key >> 32)) <= thresh) {
        const unsigned pos = atomicAdd(&scnt, 1u);
        cand[pos] = (unsigned int)(key & 0xFFFFFFFFull);
    }
    __syncthreads();

    const unsigned n = scnt;
    for (unsigned i = wave; i < n; i += 4) {
        const int c = (int)cand[i];
        const float4* er = (const float4*)(E + (size_t)c * Dn);
        const float4 e0 = er[lane * 2],            e1 = er[lane * 2 + 1];
        const float4 x0 = ((const float4*)xrow)[lane * 2];
        const float4 x1 = ((const float4*)xrow)[lane * 2 + 1];
        float s = x0.x*e0.x + x0.y*e0.y + x0.z*e0.z + x0.w*e0.w
                + x1.x*e1.x + x1.y*e1.y + x1.z*e1.z + x1.w*e1.w;
        #pragma unroll
        for (int off = 32; off > 0; off >>= 1) s += __shfl_down(s, off, 64);
        if (lane == 0) {
            const float d = esq[c] - 2.0f * s;
            atomicMin(&skey, ((u64)fkey(d) << 32) | (u64)(unsigned int)c);
        }
    }
    __syncthreads();

    const int idx = (int)(unsigned int)(skey & 0xFFFFFFFFull);
    if (t == 0) out[b] = (float)idx;
    if (t < 128) {
        const float4 x = ((const float4*)xrow)[t];
        const float4 e = ((const float4*)(E + (size_t)idx * Dn))[t];
        float4 r; r.x = x.x - e.x; r.y = x.y - e.y; r.z = x.z - e.z; r.w = x.w - e.w;
        ((float4*)(out + Bn + (size_t)b * Dn))[t] = r;
    }
}

// ---------------- fallback (round-1 fp32 path, used only if ws too small) ----
#define KSPLIT 16
#define LDSW 132
__global__ __launch_bounds__(256, 2) void argmin_fp32(
    const float* __restrict__ X, const float* __restrict__ E,
    const float* __restrict__ esq, u64* __restrict__ best)
{
    __shared__ __align__(16) float Xs[16][LDSW];
    __shared__ __align__(16) float Es[16][LDSW];
    __shared__ u64 red[128][16];
    const int tid = threadIdx.x;
    const int tx = tid & 15, ty = tid >> 4;
    const int rowTile = blockIdx.x / KSPLIT;
    const int split   = blockIdx.x % KSPLIT;
    const int m0 = rowTile * 128;
    const int kbase = split * (Kn / KSPLIT);
    float bestv[8]; int besti[8];
    #pragma unroll
    for (int i = 0; i < 8; ++i) { bestv[i] = INFINITY; besti[i] = 0; }
    const int ldRow = tid >> 2, ldD = (tid & 3) * 4;
    for (int kt = 0; kt < (Kn / KSPLIT) / 128; ++kt) {
        const int k0 = kbase + kt * 128;
        float acc[8][8] = {};
        for (int dc = 0; dc < Dn / 16; ++dc) {
            const int d0 = dc * 16;
            float4 xa = *(const float4*)&X[(size_t)(m0 + ldRow)      * Dn + d0 + ldD];
            float4 xb = *(const float4*)&X[(size_t)(m0 + 64 + ldRow) * Dn + d0 + ldD];
            float4 ea = *(const float4*)&E[(size_t)(k0 + ldRow)      * Dn + d0 + ldD];
            float4 eb = *(const float4*)&E[(size_t)(k0 + 64 + ldRow) * Dn + d0 + ldD];
            __syncthreads();
            Xs[ldD+0][ldRow] = xa.x; Xs[ldD+1][ldRow] = xa.y;
            Xs[ldD+2][ldRow] = xa.z; Xs[ldD+3][ldRow] = xa.w;
            Xs[ldD+0][64+ldRow] = xb.x; Xs[ldD+1][64+ldRow] = xb.y;
            Xs[ldD+2][64+ldRow] = xb.z; Xs[ldD+3][64+ldRow] = xb.w;
            Es[ldD+0][ldRow] = ea.x; Es[ldD+1][ldRow] = ea.y;
            Es[ldD+2][ldRow] = ea.z; Es[ldD+3][ldRow] = ea.w;
            Es[ldD+0][64+ldRow] = eb.x; Es[ldD+1][64+ldRow] = eb.y;
            Es[ldD+2][64+ldRow] = eb.z; Es[ldD+3][64+ldRow] = eb.w;
            __syncthreads();
            #pragma unroll
            for (int d = 0; d < 16; ++d) {
                float a8[8], b8[8];
                *(float4*)&a8[0] = *(const float4*)&Xs[d][4*ty];
                *(float4*)&a8[4] = *(const float4*)&Xs[d][64 + 4*ty];
                *(float4*)&b8[0] = *(const float4*)&Es[d][4*tx];
                *(float4*)&b8[4] = *(const float4*)&Es[d][64 + 4*tx];
                #pragma unroll
                for (int i = 0; i < 8; ++i)
                    #pragma unroll
                    for (int j = 0; j < 8; ++j) acc[i][j] += a8[i] * b8[j];
            }
        }
        #pragma unroll
        for (int j = 0; j < 8; ++j) {
            const int c = k0 + ((j < 4) ? (4*tx + j) : (64 + 4*tx + (j - 4)));
            const float eq = esq[c];
            #pragma unroll
            for (int i = 0; i < 8; ++i) {
                float dval = eq - 2.0f * acc[i][j];
                if (dval < bestv[i]) { bestv[i] = dval; besti[i] = c; }
            }
        }
    }
    #pragma unroll
    for (int i = 0; i < 8; ++i) {
        int rloc = (i < 4) ? (4*ty + i) : (64 + 4*ty + (i - 4));
        red[rloc][tx] = ((u64)fkey(bestv[i]) << 32) | (u64)(unsigned int)besti[i];
    }
    __syncthreads();
    if (tid < 128) {
        u64 m = red[tid][0];
        #pragma unroll
        for (int t = 1; t < 16; ++t) { u64 v = red[tid][t]; if (v < m) m = v; }
        best[(size_t)(m0 + tid) * KSPLIT + split] = m;
    }
}

__global__ __launch_bounds__(256) void finalize_kernel(
    const float* __restrict__ X, const float* __restrict__ E,
    const u64* __restrict__ best, float* __restrict__ out, int nsplits)
{
    __shared__ int sidx[2];
    const int half = threadIdx.x >> 7;
    const int t    = threadIdx.x & 127;
    const int b    = blockIdx.x * 2 + half;
    if (t < 64) {
        u64 v = (t < nsplits) ? best[(size_t)b * nsplits + t] : ~0ull;
        #pragma unroll
        for (int off = 1; off < 64; off <<= 1) {
            u64 o = __shfl_xor(v, off);
            if (o < v) v = o;
        }
        if (t == 0) {
            int idx = (int)(unsigned int)(v & 0xFFFFFFFFull);
            sidx[half] = idx;
            out[b] = (float)idx;
        }
    }
    __syncthreads();
    const int idx = sidx[half];
    float4 x = ((const float4*)(X + (size_t)b * Dn))[t];
    float4 e = ((const float4*)(E + (size_t)idx * Dn))[t];
    float4 r; r.x = x.x - e.x; r.y = x.y - e.y; r.z = x.z - e.z; r.w = x.w - e.w;
    ((float4*)(out + Bn + (size_t)b * Dn))[t] = r;
}

extern "C" void kernel_launch(void* const* d_in, const int* in_sizes, int n_in,
                              void* d_out, int out_size, void* d_ws, size_t ws_size,
                              hipStream_t stream) {
    const float* X = (const float*)d_in[0];   // previous_residual [B, D]
    const float* E = (const float*)d_in[1];   // codebook_embeddings [K, D]
    float* out = (float*)d_out;               // [B] idx-as-float ++ [B*D] residual

    // fast-path ws: esq 32KB | Xh 8MB | Eh 8MB | best 16.8MB  (~33.6 MB)
    const size_t HB = (size_t)Bn * Dn * sizeof(_Float16);        // 8 MB
    const size_t BESTB = (size_t)Bn * 256 * sizeof(u64);         // 16.8 MB
    const size_t NEED = 32768 + 2 * HB + BESTB;

    float* esq = (float*)d_ws;

    if (ws_size >= NEED) {
        _Float16* Xh = (_Float16*)((char*)d_ws + 32768);
        _Float16* Eh = (_Float16*)((char*)d_ws + 32768 + HB);
        u64* best    = (u64*)((char*)d_ws + 32768 + 2 * HB);
        esq_kernel<<<Kn / 4, 256, 0, stream>>>(E, esq);
        convert_hi<<<2048, 256, 0, stream>>>(X, E, Xh, Eh);
        argmin_hi<<<64 * 64, 256, 0, stream>>>(Xh, Eh, esq, best);
        refine_kernel<<<Bn, 256, 0, stream>>>(X, E, esq, best, out);
    } else {
        u64* best = (u64*)((char*)d_ws + 32768);
        esq_kernel<<<Kn / 4, 256, 0, stream>>>(E, esq);
        argmin_fp32<<<(Bn / 128) * KSPLIT, 256, 0, stream>>>(X, E, esq, best);
        finalize_kernel<<<Bn / 2, 256, 0, stream>>>(X, E, best, out, KSPLIT);
    }
}